// Round 6
// baseline (1172.199 us; speedup 1.0000x reference)
//
#include <hip/hip_runtime.h>

#define PP 20000

// ============================================================================
// VN linear, f32: out[p,o,i] = sum_{c<128} in[p,c,i] * W[c,o]
// Grid (625, 2): 32 whole points (96 j) x 64 outputs per block, 256 threads.
// Thread: 6 j x 4 o.  LDS: As [c][j] stride 96 (48K) + Bs [c][o] (32K) = 80 KB.
// ============================================================================
__global__ __launch_bounds__(256) void vn_gemm(const float* __restrict__ in, const float* __restrict__ Wg,
                                               float* __restrict__ out)
{
    __shared__ __align__(16) float As[128*96];
    __shared__ __align__(16) float Bs[128*64];
    const int tid = threadIdx.x;
    const int og  = tid & 15;          // 4 cols each
    const int jg  = tid >> 4;          // 6 rows each
    const int p0  = blockIdx.x * 32;
    const int o0  = blockIdx.y * 64;

    // stage A: 32 points x 384 f32, layout As[c*96 + pl*3 + i]
    for (int f = tid; f < 3072; f += 256) {
        float4 w = *(const float4*)(in + (size_t)p0*384 + f*4);
        int e = f*4;
        int pl = e/384, rem = e - pl*384;
        float vals[4] = {w.x, w.y, w.z, w.w};
        #pragma unroll
        for (int k=0;k<4;++k){
            int c = (rem+k)/3, i = (rem+k) - c*3;
            As[c*96 + pl*3 + i] = vals[k];
        }
    }
    // stage B: 128 rows x 64 cols
    for (int f = tid; f < 2048; f += 256) {
        int r = f >> 4, seg = f & 15;
        *(float4*)(Bs + r*64 + seg*4) = *(const float4*)(Wg + (size_t)r*128 + o0 + seg*4);
    }
    __syncthreads();

    float acc[6][4];
    #pragma unroll
    for (int r=0;r<6;++r)
        #pragma unroll
        for (int o=0;o<4;++o) acc[r][o]=0.f;

    #pragma unroll 2
    for (int c = 0; c < 128; ++c) {
        float2 a01 = *(const float2*)(As + c*96 + jg*6);
        float2 a23 = *(const float2*)(As + c*96 + jg*6 + 2);
        float2 a45 = *(const float2*)(As + c*96 + jg*6 + 4);
        float4 bv  = *(const float4*)(Bs + c*64 + og*4);
        float a[6] = {a01.x,a01.y,a23.x,a23.y,a45.x,a45.y};
        float bb[4] = {bv.x,bv.y,bv.z,bv.w};
        #pragma unroll
        for (int r=0;r<6;++r)
            #pragma unroll
            for (int o=0;o<4;++o) acc[r][o] += a[r]*bb[o];
    }
    #pragma unroll
    for (int pt=0;pt<2;++pt){
        int p = p0 + jg*2 + pt;
        #pragma unroll
        for (int i=0;i<3;++i){
            size_t base = (size_t)p*384 + i;
            #pragma unroll
            for (int o=0;o<4;++o)
                out[base + (size_t)(o0 + og*4 + o)*3] = acc[pt*3+i][o];
        }
    }
}

// ============================================================================
// Attention scores: one block (128 threads) per point.  Reads q from its own
// d_out row (fully, before any write) + gathered k rows (ws) -> computes
// softmax'd attention weights, stores 128 f32 (att[n*8+h]) into the first 128
// floats of ITS OWN d_out row.  Per-point in-place: race-free.
// ============================================================================
__global__ __launch_bounds__(128) void attn_score(
    const float* qf, const float* __restrict__ kf,
    const float* __restrict__ sh, const float* __restrict__ dist, const int* __restrict__ idxp,
    const float* __restrict__ gw1, const float* __restrict__ gb1,
    const float* __restrict__ gw2, const float* __restrict__ gb2,
    float* att)
{
    const int p = blockIdx.x, c = threadIdx.x;
    __shared__ float dot_s[16*132];
    __shared__ float pos_s[16*132];
    __shared__ float sh_s[48];
    __shared__ int   nidx[16];
    __shared__ float w1_s[128*8];
    __shared__ float w2_s[64], b1_s[8], b2_s[8];
    __shared__ float u2_s[16*8], logit_s[16*8];

    if (c < 16) nidx[c] = idxp[p*16 + c];
    if (c < 48) sh_s[c] = sh[(size_t)p*51 + 3 + c];   // sh[:,1:,:]
    #pragma unroll
    for (int j=0;j<8;++j) w1_s[c*8+j] = gw1[c*8+j];
    if (c < 64) w2_s[c] = gw2[c];
    if (c < 8){ b1_s[c]=gb1[c]; b2_s[c]=gb2[c]; }
    size_t qa = (size_t)p*384 + c*3;
    float qx = qf[qa], qy = qf[qa+1], qz = qf[qa+2];
    __syncthreads();

    for (int n=0;n<16;++n){
        size_t kbase = (size_t)nidx[n]*384 + c*3;
        float kx = kf[kbase], ky = kf[kbase+1], kz = kf[kbase+2];
        dot_s[n*132 + c] = kx*qx + ky*qy + kz*qz;
        pos_s[n*132 + c] = (kx-qx)*sh_s[n*3] + (ky-qy)*sh_s[n*3+1] + (kz-qz)*sh_s[n*3+2];
    }
    __syncthreads();

    // 128 tasks = (n,h): head-dot reduction + pos-MLP layer 1
    const int tn = c >> 3, th = c & 7;
    float dsum = 0.f;
    #pragma unroll
    for (int s=0;s<16;++s) dsum += dot_s[tn*132 + th*16 + s];
    float uj = b1_s[th];
    for (int cc=0; cc<128; ++cc) uj += pos_s[tn*132 + cc] * w1_s[cc*8 + th];
    u2_s[tn*8+th] = fmaxf(uj, 0.f);
    __syncthreads();

    float l = b2_s[th];
    #pragma unroll
    for (int j=0;j<8;++j) l += u2_s[tn*8+j]*w2_s[j*8+th];
    l += dsum + dist[(size_t)p*128 + tn*8 + th];
    logit_s[tn*8+th] = l * 0.25f;                 // / sqrt(DPH=16)
    __syncthreads();

    // softmax over n per head; write att to own d_out row (q fully read by now)
    if (c < 8){
        float mx = -3.0e38f;
        #pragma unroll
        for (int n=0;n<16;++n) mx = fmaxf(mx, logit_s[n*8+c]);
        float e[16], ssum = 0.f;
        #pragma unroll
        for (int n=0;n<16;++n){ e[n] = __expf(logit_s[n*8+c]-mx); ssum += e[n]; }
        float inv = 1.f/ssum;
        #pragma unroll
        for (int n=0;n<16;++n) att[(size_t)p*384 + n*8 + c] = e[n]*inv;
    }
}

// ============================================================================
// Attention apply: one block (128 threads) per point.  Stages its own row's
// att (128 f32) to LDS, then overwrites its own row with tgt2 = sum_n att*v.
// ============================================================================
__global__ __launch_bounds__(128) void attn_apply(const float* __restrict__ vv,
                                                  const int* __restrict__ idxp,
                                                  float* io)
{
    const int p = blockIdx.x, c = threadIdx.x;
    __shared__ float att_s[128];
    __shared__ int   nidx[16];
    if (c < 16) nidx[c] = idxp[p*16 + c];
    att_s[c] = io[(size_t)p*384 + c];      // att[n*8+h] layout
    __syncthreads();                        // all io-row reads complete

    const int h = c >> 4;
    float ax=0.f, ay=0.f, az=0.f;
    #pragma unroll
    for (int n=0;n<16;++n){
        float wgt = att_s[n*8+h];
        size_t vb = (size_t)nidx[n]*384 + c*3;
        ax += wgt*vv[vb]; ay += wgt*vv[vb+1]; az += wgt*vv[vb+2];
    }
    size_t ob = (size_t)p*384 + c*3;
    io[ob] = ax; io[ob+1] = ay; io[ob+2] = az;
}

// ============================================================================
// Fused FF, f32: h = VNrelu(y@fw1, y@fd1); out = h@fw2.
// 32 chunks of 16 DFF cols.  LDS: As 48K + Bu/Bd/W2s 8K each + Hs 6K = 78 KB.
// ============================================================================
__global__ __launch_bounds__(256) void vn_ff(const float* __restrict__ in,
                                             const float* __restrict__ W1, const float* __restrict__ Wd,
                                             const float* __restrict__ W2, float* __restrict__ out)
{
    __shared__ __align__(16) float As[128*96];
    __shared__ __align__(16) float Bu[128*16];
    __shared__ __align__(16) float Bd[128*16];
    __shared__ __align__(16) float W2s[16*128];
    __shared__ __align__(16) float Hs[16*96];
    const int tid = threadIdx.x;
    const int og  = tid & 15;
    const int jg  = tid >> 4;
    const int p0  = blockIdx.x * 32;

    for (int f = tid; f < 3072; f += 256) {
        float4 w = *(const float4*)(in + (size_t)p0*384 + f*4);
        int e = f*4;
        int pl = e/384, rem = e - pl*384;
        float vals[4] = {w.x, w.y, w.z, w.w};
        #pragma unroll
        for (int k=0;k<4;++k){
            int c = (rem+k)/3, i = (rem+k) - c*3;
            As[c*96 + pl*3 + i] = vals[k];
        }
    }

    float acc2[6][8];
    #pragma unroll
    for (int r=0;r<6;++r)
        #pragma unroll
        for (int o=0;o<8;++o) acc2[r][o]=0.f;

    for (int ch = 0; ch < 32; ++ch) {
        const int col0 = ch*16;
        for (int f = tid; f < 512; f += 256) {          // 128 rows x 4 quads
            int r = f >> 2, seg = f & 3;
            *(float4*)(Bu + r*16 + seg*4) = *(const float4*)(W1 + (size_t)r*512 + col0 + seg*4);
            *(float4*)(Bd + r*16 + seg*4) = *(const float4*)(Wd + (size_t)r*512 + col0 + seg*4);
        }
        for (int f = tid; f < 512; f += 256) {          // 16 rows x 32 quads
            int r = f >> 5, seg = f & 31;
            *(float4*)(W2s + r*128 + seg*4) = *(const float4*)(W2 + (size_t)(col0 + r)*128 + seg*4);
        }
        __syncthreads();

        float au[6], ad[6];
        #pragma unroll
        for (int r=0;r<6;++r){ au[r]=0.f; ad[r]=0.f; }
        #pragma unroll 2
        for (int c = 0; c < 128; ++c) {
            float2 a01 = *(const float2*)(As + c*96 + jg*6);
            float2 a23 = *(const float2*)(As + c*96 + jg*6 + 2);
            float2 a45 = *(const float2*)(As + c*96 + jg*6 + 4);
            float b1 = Bu[c*16 + og];
            float b2 = Bd[c*16 + og];
            float a[6] = {a01.x,a01.y,a23.x,a23.y,a45.x,a45.y};
            #pragma unroll
            for (int r=0;r<6;++r){ au[r] += a[r]*b1; ad[r] += a[r]*b2; }
        }
        // VN-relu per point -> Hs[fcol][j]
        #pragma unroll
        for (int pt=0;pt<2;++pt){
            float ux=au[pt*3+0], uy=au[pt*3+1], uz=au[pt*3+2];
            float dx=ad[pt*3+0], dy=ad[pt*3+1], dz=ad[pt*3+2];
            float dot = ux*dx + uy*dy + uz*dz;
            float ksq = dx*dx + dy*dy + dz*dz;
            if (dot < 0.f){
                float fc = dot/(ksq + 1e-6f);
                ux -= fc*dx; uy -= fc*dy; uz -= fc*dz;
            }
            Hs[og*96 + jg*6 + pt*3    ] = ux;
            Hs[og*96 + jg*6 + pt*3 + 1] = uy;
            Hs[og*96 + jg*6 + pt*3 + 2] = uz;
        }
        __syncthreads();
        // acc2 += h-chunk @ fw2-chunk
        #pragma unroll 2
        for (int cc = 0; cc < 16; ++cc) {
            float2 h01 = *(const float2*)(Hs + cc*96 + jg*6);
            float2 h23 = *(const float2*)(Hs + cc*96 + jg*6 + 2);
            float2 h45 = *(const float2*)(Hs + cc*96 + jg*6 + 4);
            float4 w0 = *(const float4*)(W2s + cc*128 + og*8);
            float4 w1 = *(const float4*)(W2s + cc*128 + og*8 + 4);
            float h[6] = {h01.x,h01.y,h23.x,h23.y,h45.x,h45.y};
            float wb[8] = {w0.x,w0.y,w0.z,w0.w,w1.x,w1.y,w1.z,w1.w};
            #pragma unroll
            for (int r=0;r<6;++r)
                #pragma unroll
                for (int o=0;o<8;++o) acc2[r][o] += h[r]*wb[o];
        }
        __syncthreads();
    }
    #pragma unroll
    for (int pt=0;pt<2;++pt){
        int p = p0 + jg*2 + pt;
        #pragma unroll
        for (int i=0;i<3;++i){
            size_t base = (size_t)p*384 + i;
            #pragma unroll
            for (int o=0;o<8;++o)
                out[base + (size_t)(og*8+o)*3] = acc2[pt*3+i][o];
        }
    }
}

// ============================================================================
// VN layernorm: r = a + b2; stats over 128 channel norms.  Element-wise
// in-place (out aliasing a or b2) is race-free.
// ============================================================================
__global__ __launch_bounds__(256) void vn_ln(const float* __restrict__ a, const float* b2,
                                             const float* __restrict__ gamma, const float* __restrict__ beta,
                                             float* out)
{
    const int tid = threadIdx.x;
    const int pl = tid >> 7, c = tid & 127;
    const int p = blockIdx.x*2 + pl;
    size_t base = (size_t)p*384 + c*3;
    float rx = a[base]   + b2[base];
    float ry = a[base+1] + b2[base+1];
    float rz = a[base+2] + b2[base+2];
    float nc = sqrtf(rx*rx + ry*ry + rz*rz);
    float s1 = nc, s2 = nc*nc;
    for (int off=32; off; off>>=1){ s1 += __shfl_down(s1, off); s2 += __shfl_down(s2, off); }
    __shared__ float pr[4][2];
    if ((tid & 63) == 0){ pr[tid>>6][0] = s1; pr[tid>>6][1] = s2; }
    __syncthreads();
    float S1 = pr[pl*2][0] + pr[pl*2+1][0];
    float S2 = pr[pl*2][1] + pr[pl*2+1][1];
    float mu  = S1*(1.f/128.f);
    float var = S2*(1.f/128.f) - mu*mu;
    float nh = (nc - mu)*rsqrtf(var + 1e-5f)*gamma[c] + beta[c];
    float sc = nh/(nc + 1e-6f);
    out[base] = rx*sc; out[base+1] = ry*sc; out[base+2] = rz*sc;
}

// ============================================================================
extern "C" void kernel_launch(void* const* d_in, const int* in_sizes, int n_in,
                              void* d_out, int out_size, void* d_ws, size_t ws_size,
                              hipStream_t stream)
{
    const float* tgt  = (const float*)d_in[0];
    const float* mem  = (const float*)d_in[1];
    const float* sh   = (const float*)d_in[2];
    const float* dist = (const float*)d_in[3];
    const float* Wq   = (const float*)d_in[4];
    const float* Wk   = (const float*)d_in[5];
    const float* Wv   = (const float*)d_in[6];
    const float* Wo   = (const float*)d_in[7];
    const float* gw1  = (const float*)d_in[8];
    const float* gb1  = (const float*)d_in[9];
    const float* gw2  = (const float*)d_in[10];
    const float* gb2  = (const float*)d_in[11];
    const float* ln1g = (const float*)d_in[12];
    const float* ln1b = (const float*)d_in[13];
    const float* ln2g = (const float*)d_in[14];
    const float* ln2b = (const float*)d_in[15];
    const float* fw1  = (const float*)d_in[16];
    const float* fd1  = (const float*)d_in[17];
    const float* fw2  = (const float*)d_in[18];
    const int*   idx  = (const int*)d_in[19];
    // d_in[20], d_in[21] (cnt1, cnt2) unused by the reference.

    // Workspace: EXACTLY 30,720,000 bytes (the size proven functional in R3).
    // d_out (30.72 MB) doubles as the second buffer with per-point in-place
    // row reuse (race-free; see kernel comments).
    //   1. kb = mem@Wk (f32)            -> ws
    //   2. q  = tgt@Wq (f32)            -> d_out
    //   3. attn_score(q, kb)            -> att into own d_out rows
    //   4. vv = mem@Wv (f32)            -> ws        (kb dead)
    //   5. attn_apply(vv, att)          -> tgt2 into own d_out rows
    //   6. t2w = d_out@Wo (f32)         -> ws        (vv dead)
    //   7. LN1(tgt, t2w)                -> ws (in-place)
    //   8. vn_ff(y)                     -> d_out     (tgt2 dead)
    //   9. LN2(y, ffo)                  -> d_out (in-place)
    float* wsf = (float*)d_ws;
    float* outf = (float*)d_out;

    dim3 g2(625,2);
    vn_gemm<<<g2,256,0,stream>>>(mem, Wk, wsf);
    vn_gemm<<<g2,256,0,stream>>>(tgt, Wq, outf);
    attn_score<<<PP,128,0,stream>>>(outf, wsf, sh, dist, idx, gw1, gb1, gw2, gb2, outf);
    vn_gemm<<<g2,256,0,stream>>>(mem, Wv, wsf);
    attn_apply<<<PP,128,0,stream>>>(wsf, idx, outf);
    vn_gemm<<<g2,256,0,stream>>>(outf, Wo, wsf);
    vn_ln<<<PP/2,256,0,stream>>>(tgt, wsf, ln1g, ln1b, wsf);
    vn_ff<<<625,256,0,stream>>>(wsf, fw1, fd1, fw2, outf);
    vn_ln<<<PP/2,256,0,stream>>>(wsf, outf, ln2g, ln2b, outf);
}